// Round 7
// baseline (416.959 us; speedup 1.0000x reference)
//
#include <hip/hip_runtime.h>
#include <math.h>

#define KNN  20
#define INFK 0xFFFFFFFFu

typedef _Float16 half8 __attribute__((ext_vector_type(8)));
typedef float    f32x4 __attribute__((ext_vector_type(4)));

// ---- DPP wave64 min-reduction (u32), broadcast via readlane ----------------
#define DPP_MIN_STEP(v, ctrl, rm)                                              \
    {                                                                          \
        unsigned _t = (unsigned)__builtin_amdgcn_update_dpp(                   \
            (int)(v), (int)(v), (ctrl), (rm), 0xf, false);                     \
        (v) = ((v) < _t) ? (v) : _t;                                           \
    }

__device__ __forceinline__ unsigned wave_min_bcast(unsigned v) {
    DPP_MIN_STEP(v, 0x111, 0xf);   // row_shr:1
    DPP_MIN_STEP(v, 0x112, 0xf);   // row_shr:2
    DPP_MIN_STEP(v, 0x114, 0xf);   // row_shr:4
    DPP_MIN_STEP(v, 0x118, 0xf);   // row_shr:8
    DPP_MIN_STEP(v, 0x142, 0xa);   // row_bcast:15
    DPP_MIN_STEP(v, 0x143, 0xc);   // row_bcast:31
    return (unsigned)__builtin_amdgcn_readlane((int)v, 63);
}

#define CE(a, b)                                                               \
    { unsigned _lo = ((a) < (b)) ? (a) : (b);                                  \
      unsigned _hi = ((a) < (b)) ? (b) : (a); (a) = _lo; (b) = _hi; }

__device__ __forceinline__ void insert4(unsigned (&cd)[4], unsigned key) {
    #pragma unroll
    for (int i = 0; i < 4; ++i) CE(cd[i], key);
}

__device__ __forceinline__ void merge44(unsigned (&a)[4], unsigned (&b)[4],
                                        unsigned (&o)[8]) {
    CE(a[0], b[0]); CE(a[1], b[1]); CE(a[2], b[2]); CE(a[3], b[3]);
    CE(a[2], b[0]); CE(a[3], b[1]);
    CE(a[1], a[2]); CE(a[3], b[0]); CE(b[1], b[2]);
    o[0] = a[0]; o[1] = a[1]; o[2] = a[2]; o[3] = a[3];
    o[4] = b[0]; o[5] = b[1]; o[6] = b[2]; o[7] = b[3];
}

// 20-round all-register merge; lane r ends holding neighbor index r.
__device__ __forceinline__ int merge20(unsigned (&cd)[8], int t) {
    int nbrv = 0;
    #pragma unroll
    for (int r = 0; r < KNN; ++r) {
        const unsigned bk = wave_min_bcast(cd[0]);
        nbrv = (t == r) ? (int)(bk & 511u) : nbrv;
        const bool win = (cd[0] == bk);
        #pragma unroll
        for (int i = 0; i < 7; ++i) cd[i] = win ? cd[i + 1] : cd[i];
        cd[7] = win ? INFK : cd[7];
    }
    return nbrv;
}

__device__ __forceinline__ float dot16(const float4& o0, const float4& o1,
                                       const float4& o2, const float4& o3,
                                       const float4& a0, const float4& a1,
                                       const float4& a2, const float4& a3) {
    float d0 = 0.f, d1 = 0.f, d2 = 0.f, d3 = 0.f;
    d0 = fmaf(o0.x, a0.x, d0); d0 = fmaf(o0.y, a0.y, d0); d0 = fmaf(o0.z, a0.z, d0); d0 = fmaf(o0.w, a0.w, d0);
    d1 = fmaf(o1.x, a1.x, d1); d1 = fmaf(o1.y, a1.y, d1); d1 = fmaf(o1.z, a1.z, d1); d1 = fmaf(o1.w, a1.w, d1);
    d2 = fmaf(o2.x, a2.x, d2); d2 = fmaf(o2.y, a2.y, d2); d2 = fmaf(o2.z, a2.z, d2); d2 = fmaf(o2.w, a2.w, d2);
    d3 = fmaf(o3.x, a3.x, d3); d3 = fmaf(o3.y, a3.y, d3); d3 = fmaf(o3.z, a3.z, d3); d3 = fmaf(o3.w, a3.w, d3);
    return (d0 + d1) + (d2 + d3);
}

__device__ __forceinline__ void scan_candidates(const float* __restrict__ base,
                                                const float* __restrict__ ssq,
                                                float sqn, int t,
                                                const float4& o0, const float4& o1,
                                                const float4& o2, const float4& o3,
                                                unsigned (&cd)[8]) {
    unsigned ca[4], cb[4];
    #pragma unroll
    for (int i = 0; i < 4; ++i) { ca[i] = INFK; cb[i] = INFK; }
    #pragma unroll
    for (int j = 0; j < 8; ++j) {
        const int m = j * 64 + t;
        const float4* p = (const float4*)(base + m * 16);
        const float4 a0 = p[0], a1 = p[1], a2 = p[2], a3 = p[3];
        const float dot = dot16(o0, o1, o2, o3, a0, a1, a2, a3);
        float vd = fmaxf(sqn + ssq[m] - 2.f * dot, 0.f);
        const unsigned key = (__float_as_uint(vd) & 0xFFFFFE00u) | (unsigned)m;
        if (j < 4) insert4(ca, key); else insert4(cb, key);
    }
    merge44(ca, cb, cd);
}

// ---------------------------------------------------------------------------
// Fused kernel: stage1 -> per-batch release/acquire sync -> stage2.
// 2048 blocks x 256 threads; __launch_bounds__(256,8) + LDS<=20KB guarantees
// full co-residency (8 blocks/CU x 256 CU = whole grid), so the per-batch
// spin cannot deadlock. clock64 valve converts any logic error into a
// visible wrong answer instead of a hang.
// ---------------------------------------------------------------------------
__global__ __launch_bounds__(256, 8)
void fused_kernel(const float* __restrict__ x, const float* __restrict__ w_fm1,
                  const float* __restrict__ w_fm2, const float* __restrict__ w_mix1,
                  const float* __restrict__ w_mix2, const float* __restrict__ m_last,
                  const float* __restrict__ b_cls, const float* __restrict__ w_cls,
                  float* __restrict__ R, float* __restrict__ sqr,
                  half8* __restrict__ Bf, f32x4* __restrict__ Mf,
                  unsigned* __restrict__ ctr, float* __restrict__ out) {
    __shared__ float ssq[512];          // phase1: x-norms; phase2: R-norms
    __shared__ float swn[KNN];
    __shared__ union {
        struct { float wcs[630]; float smix2[1500]; } prep;   // phase1 (first blocks)
        struct { float NRs[4][344]; float pool4[4]; } ph2;    // phase2
    } u;
    const int tid   = threadIdx.x;
    const int bidx  = blockIdx.x;
    const int batch = bidx >> 7;
    const bool first = (bidx & 127) == 0;
    const float* xb = x + (size_t)batch * 8192;

    // ---------------- phase 1: stage1 ----------------
    if (first && tid < 40) out[batch * 40 + tid] = b_cls[tid];

    if (tid < KNN) {
        float v[KNN]; float mx = -__builtin_inff();
        #pragma unroll
        for (int k = 0; k < KNN; ++k) { v[k] = w_fm1[k]; mx = fmaxf(mx, v[k]); }
        float s = 0.f;
        #pragma unroll
        for (int k = 0; k < KNN; ++k) { v[k] = __expf(v[k] - mx); s += v[k]; }
        swn[tid] = v[tid] / s;
    }

    if (first) {
        for (int e = tid; e < 1500; e += 256) u.prep.smix2[e] = w_mix2[e];
        if (tid < 30) {
            float wr[KNN]; float mx = -__builtin_inff();
            #pragma unroll
            for (int k = 0; k < KNN; ++k) { wr[k] = w_fm2[tid * KNN + k]; mx = fmaxf(mx, wr[k]); }
            float s = 0.f;
            #pragma unroll
            for (int k = 0; k < KNN; ++k) { wr[k] = __expf(wr[k] - mx); s += wr[k]; }
            const float scale = w_mix1[tid] / s;
            #pragma unroll
            for (int k = 0; k < KNN; ++k) u.prep.wcs[tid * 21 + k] = wr[k] * scale;
        }
    }

    for (int m = tid; m < 512; m += 256) {
        const float4* p = (const float4*)(xb + m * 16);
        const float4 a0 = p[0], a1 = p[1], a2 = p[2], a3 = p[3];
        ssq[m] = dot16(a0, a1, a2, a3, a0, a1, a2, a3);
    }
    __syncthreads();

    if (first) {
        // MFMA fragment tables for this batch (B: Q in f16, M: m_last), per-lane:
        //   B[k=(lane>>4)*8+j][f=tile*16+(lane&15)], C/D row=(lane>>4)*4+reg.
        const int lane = tid & 63, tile = tid >> 6;
        const int q = lane >> 4, c = lane & 15;
        const int f = tile * 16 + c;
        half8 hb;
        #pragma unroll
        for (int j = 0; j < 8; ++j) {
            const int k = q * 8 + j;
            float val = 0.f;
            if (k < KNN && f < 50) {
                #pragma unroll
                for (int cc = 0; cc < 30; ++cc)
                    val = fmaf(u.prep.wcs[cc * 21 + k], u.prep.smix2[cc * 50 + f], val);
            }
            hb[j] = (_Float16)val;
        }
        Bf[batch * 256 + tile * 64 + lane] = hb;
        f32x4 mf;
        #pragma unroll
        for (int r = 0; r < 4; ++r)
            mf[r] = (f < 50) ? m_last[(q * 4 + r) * 50 + f] : 0.f;
        Mf[batch * 256 + tile * 64 + lane] = mf;
    }

    const int t = tid & 63, w = tid >> 6;
    const int row = bidx * 4 + w;
    const int n = row & 511;

    {
        const float4* xn4 = (const float4*)(xb + n * 16);
        const float4 o0 = xn4[0], o1 = xn4[1], o2 = xn4[2], o3 = xn4[3];
        unsigned cd[8];
        scan_candidates(xb, ssq, ssq[n], t, o0, o1, o2, o3, cd);
        const int nbrv = merge20(cd, t);

        float nrf[5];
        #pragma unroll
        for (int j = 0; j < 5; ++j) {
            const int e = j * 64 + t;
            const int nb = __shfl(nbrv, e >> 4, 64);
            nrf[j] = xb[nb * 16 + (e & 15)];
        }
        const int kq = t >> 4;
        float part = 0.f;
        #pragma unroll
        for (int j = 0; j < 5; ++j) part = fmaf(swn[j * 4 + kq], nrf[j], part);
        part += __shfl_xor(part, 16, 64);
        part += __shfl_xor(part, 32, 64);
        const float racc = part;
        if (t < 16) R[(size_t)row * 16 + t] = racc;

        // ||R||^2 via butterfly (self-dist error ~1ulp << nn-gap; clamped >=0)
        float q2 = racc * racc;
        q2 += __shfl_xor(q2, 1, 64);
        q2 += __shfl_xor(q2, 2, 64);
        q2 += __shfl_xor(q2, 4, 64);
        q2 += __shfl_xor(q2, 8, 64);
        if (t == 0) sqr[row] = q2;
    }

    // ---------------- per-batch sync ----------------
    __syncthreads();
    unsigned* cb = ctr + batch * 16;     // 64B-strided counters
    if (tid == 0) {
        __threadfence();
        __hip_atomic_fetch_add(cb, 1u, __ATOMIC_RELEASE, __HIP_MEMORY_SCOPE_AGENT);
        long long t0 = clock64();
        while (__hip_atomic_load(cb, __ATOMIC_ACQUIRE, __HIP_MEMORY_SCOPE_AGENT) < 128u) {
            __builtin_amdgcn_s_sleep(8);
            if (clock64() - t0 > 100000000LL) break;   // safety valve (~40ms)
        }
        __threadfence();
    }
    __syncthreads();

    // ---------------- phase 2: stage2 ----------------
    const float* Rb = R + (size_t)batch * 8192;
    for (int m = tid; m < 512; m += 256) ssq[m] = sqr[batch * 512 + m];
    __syncthreads();

    const float4* rn4 = (const float4*)(Rb + n * 16);
    const float4 o0 = rn4[0], o1 = rn4[1], o2 = rn4[2], o3 = rn4[3];
    unsigned cd[8];
    scan_candidates(Rb, ssq, ssq[n], t, o0, o1, o2, o3, cd);
    const int nbrv = merge20(cd, t);

    #pragma unroll
    for (int j = 0; j < 5; ++j) {
        const int e = j * 64 + t;
        const int nb = __shfl(nbrv, e >> 4, 64);
        u.ph2.NRs[w][(e >> 4) * 17 + (e & 15)] = Rb[nb * 16 + (e & 15)];
    }

    const int q = t >> 4, c = t & 15;
    half8 af;
    #pragma unroll
    for (int j = 0; j < 8; ++j) {
        const int k = q * 8 + j;
        af[j] = (k < KNN) ? (_Float16)u.ph2.NRs[w][k * 17 + c] : (_Float16)0.f;
    }

    float dsum = 0.f;
    #pragma unroll
    for (int tile = 0; tile < 4; ++tile) {
        const half8 bf = Bf[batch * 256 + tile * 64 + t];
        const f32x4 mf = Mf[batch * 256 + tile * 64 + t];
        f32x4 acc = {0.f, 0.f, 0.f, 0.f};
        acc = __builtin_amdgcn_mfma_f32_16x16x32_f16(af, bf, acc, 0, 0, 0);
        float a2 = 0.f;
        #pragma unroll
        for (int r = 0; r < 4; ++r) {
            const float diff = acc[r] - mf[r];
            a2 = fmaf(diff, diff, a2);
        }
        a2 += __shfl_xor(a2, 16, 64);
        a2 += __shfl_xor(a2, 32, 64);
        const int f = tile * 16 + c;
        dsum += (f < 50) ? sqrtf(a2 + 1e-8f) : 0.f;
    }
    #pragma unroll
    for (int off = 32; off >= 1; off >>= 1) dsum += __shfl_xor(dsum, off, 64);
    if (t == 0) u.ph2.pool4[w] = dsum * (1.0f / 200.0f);
    __syncthreads();

    if (tid < 40) {
        const int n0 = (bidx * 4) & 511;
        float a = 0.f;
        #pragma unroll
        for (int i = 0; i < 4; ++i)
            a = fmaf(u.ph2.pool4[i], w_cls[(n0 + i) * 40 + tid], a);
        unsafeAtomicAdd(&out[batch * 40 + tid], a);
    }
}

extern "C" void kernel_launch(void* const* d_in, const int* in_sizes, int n_in,
                              void* d_out, int out_size, void* d_ws, size_t ws_size,
                              hipStream_t stream) {
    const float* x      = (const float*)d_in[0];
    const float* w_fm1  = (const float*)d_in[1];
    const float* w_mix1 = (const float*)d_in[2];
    const float* w_fm2  = (const float*)d_in[3];
    const float* w_mix2 = (const float*)d_in[4];
    const float* m_last = (const float*)d_in[5];
    const float* w_cls  = (const float*)d_in[6];
    const float* b_cls  = (const float*)d_in[7];
    float* out = (float*)d_out;

    float*    ws   = (float*)d_ws;
    float*    R    = ws;                          // 131072 floats
    float*    sqrb = ws + 131072;                 // 8192 floats
    half8*    Bf   = (half8*)(ws + 139264);       // 16 batches x 256 x 16B
    f32x4*    Mf   = (f32x4*)(ws + 155648);       // 16 batches x 256 x 16B
    unsigned* ctr  = (unsigned*)(ws + 172032);    // 16 counters, 64B stride

    hipMemsetAsync(ctr, 0, 16 * 64, stream);
    fused_kernel<<<2048, 256, 0, stream>>>(x, w_fm1, w_fm2, w_mix1, w_mix2,
                                           m_last, b_cls, w_cls,
                                           R, sqrb, Bf, Mf, ctr, out);
}

// Round 8
// 122.114 us; speedup vs baseline: 3.4145x; 3.4145x over previous
//
#include <hip/hip_runtime.h>
#include <math.h>

#define KNN  20
#define INFK 0xFFFFFFFFu

typedef _Float16 half8 __attribute__((ext_vector_type(8)));
typedef float    f32x4 __attribute__((ext_vector_type(4)));

// ---- DPP wave64 min-reduction (u32), broadcast via readlane ----------------
#define DPP_MIN_STEP(v, ctrl, rm)                                              \
    {                                                                          \
        unsigned _t = (unsigned)__builtin_amdgcn_update_dpp(                   \
            (int)(v), (int)(v), (ctrl), (rm), 0xf, false);                     \
        (v) = ((v) < _t) ? (v) : _t;                                           \
    }

__device__ __forceinline__ unsigned wave_min_bcast(unsigned v) {
    DPP_MIN_STEP(v, 0x111, 0xf);   // row_shr:1
    DPP_MIN_STEP(v, 0x112, 0xf);   // row_shr:2
    DPP_MIN_STEP(v, 0x114, 0xf);   // row_shr:4
    DPP_MIN_STEP(v, 0x118, 0xf);   // row_shr:8
    DPP_MIN_STEP(v, 0x142, 0xa);   // row_bcast:15
    DPP_MIN_STEP(v, 0x143, 0xc);   // row_bcast:31
    return (unsigned)__builtin_amdgcn_readlane((int)v, 63);
}

#define CE(a, b)                                                               \
    { unsigned _lo = ((a) < (b)) ? (a) : (b);                                  \
      unsigned _hi = ((a) < (b)) ? (b) : (a); (a) = _lo; (b) = _hi; }

__device__ __forceinline__ void insert4(unsigned (&cd)[4], unsigned key) {
    #pragma unroll
    for (int i = 0; i < 4; ++i) CE(cd[i], key);
}

__device__ __forceinline__ void merge44(unsigned (&a)[4], unsigned (&b)[4],
                                        unsigned (&o)[8]) {
    CE(a[0], b[0]); CE(a[1], b[1]); CE(a[2], b[2]); CE(a[3], b[3]);
    CE(a[2], b[0]); CE(a[3], b[1]);
    CE(a[1], a[2]); CE(a[3], b[0]); CE(b[1], b[2]);
    o[0] = a[0]; o[1] = a[1]; o[2] = a[2]; o[3] = a[3];
    o[4] = b[0]; o[5] = b[1]; o[6] = b[2]; o[7] = b[3];
}

// 20-round all-register merge; lane r ends holding neighbor index r.
__device__ __forceinline__ int merge20(unsigned (&cd)[8], int t) {
    int nbrv = 0;
    #pragma unroll
    for (int r = 0; r < KNN; ++r) {
        const unsigned bk = wave_min_bcast(cd[0]);
        nbrv = (t == r) ? (int)(bk & 511u) : nbrv;
        const bool win = (cd[0] == bk);
        #pragma unroll
        for (int i = 0; i < 7; ++i) cd[i] = win ? cd[i + 1] : cd[i];
        cd[7] = win ? INFK : cd[7];
    }
    return nbrv;
}

// canonical 4-chain dot; ALL sq/dot use this -> m==n diagonal exactly 0
__device__ __forceinline__ float dot16(const float4& o0, const float4& o1,
                                       const float4& o2, const float4& o3,
                                       const float4& a0, const float4& a1,
                                       const float4& a2, const float4& a3) {
    float d0 = 0.f, d1 = 0.f, d2 = 0.f, d3 = 0.f;
    d0 = fmaf(o0.x, a0.x, d0); d0 = fmaf(o0.y, a0.y, d0); d0 = fmaf(o0.z, a0.z, d0); d0 = fmaf(o0.w, a0.w, d0);
    d1 = fmaf(o1.x, a1.x, d1); d1 = fmaf(o1.y, a1.y, d1); d1 = fmaf(o1.z, a1.z, d1); d1 = fmaf(o1.w, a1.w, d1);
    d2 = fmaf(o2.x, a2.x, d2); d2 = fmaf(o2.y, a2.y, d2); d2 = fmaf(o2.z, a2.z, d2); d2 = fmaf(o2.w, a2.w, d2);
    d3 = fmaf(o3.x, a3.x, d3); d3 = fmaf(o3.y, a3.y, d3); d3 = fmaf(o3.z, a3.z, d3); d3 = fmaf(o3.w, a3.w, d3);
    return (d0 + d1) + (d2 + d3);
}

// candidate scan with INLINE candidate norms (no LDS, no barrier; diag exact 0)
__device__ __forceinline__ void scan_candidates(const float* __restrict__ base,
                                                float sqn, int t,
                                                const float4& o0, const float4& o1,
                                                const float4& o2, const float4& o3,
                                                unsigned (&cd)[8]) {
    unsigned ca[4], cb[4];
    #pragma unroll
    for (int i = 0; i < 4; ++i) { ca[i] = INFK; cb[i] = INFK; }
    #pragma unroll
    for (int j = 0; j < 8; ++j) {
        const int m = j * 64 + t;
        const float4* p = (const float4*)(base + m * 16);
        const float4 a0 = p[0], a1 = p[1], a2 = p[2], a3 = p[3];
        const float dot = dot16(o0, o1, o2, o3, a0, a1, a2, a3);
        const float sqm = dot16(a0, a1, a2, a3, a0, a1, a2, a3);
        float vd = fmaxf(sqn + sqm - 2.f * dot, 0.f);      // exact 0 at m==n
        const unsigned key = (__float_as_uint(vd) & 0xFFFFFE00u) | (unsigned)m;
        if (j < 4) insert4(ca, key); else insert4(cb, key);
    }
    merge44(ca, cb, cd);
}

// ---------------------------------------------------------------------------
// Stage 1: KNN on raw points + wFM -> R. Barrier-free per-wave path; block 0
// builds the MFMA fragment tables (Q in f16, m_last) for stage2; the first
// block of each batch initializes out with the classifier bias.
// ---------------------------------------------------------------------------
__global__ __launch_bounds__(256)
void stage1_kernel(const float* __restrict__ x, const float* __restrict__ w_fm1,
                   const float* __restrict__ w_fm2, const float* __restrict__ w_mix1,
                   const float* __restrict__ w_mix2, const float* __restrict__ m_last,
                   const float* __restrict__ b_cls,
                   float* __restrict__ R,
                   half8* __restrict__ Bf, f32x4* __restrict__ Mf,
                   float* __restrict__ out) {
    __shared__ float wcs[630];       // only block 0 touches these
    __shared__ float smix2[1500];
    const int tid   = threadIdx.x;
    const int bidx  = blockIdx.x;
    const int batch = bidx >> 7;
    const float* xb = x + (size_t)batch * 8192;

    if ((bidx & 127) == 0 && tid < 40)
        out[batch * 40 + tid] = b_cls[tid];

    if (bidx == 0) {                 // one-time fragment-table build
        for (int e = tid; e < 1500; e += 256) smix2[e] = w_mix2[e];
        if (tid < 30) {
            float wr[KNN]; float mx = -__builtin_inff();
            #pragma unroll
            for (int k = 0; k < KNN; ++k) { wr[k] = w_fm2[tid * KNN + k]; mx = fmaxf(mx, wr[k]); }
            float s = 0.f;
            #pragma unroll
            for (int k = 0; k < KNN; ++k) { wr[k] = __expf(wr[k] - mx); s += wr[k]; }
            const float scale = w_mix1[tid] / s;
            #pragma unroll
            for (int k = 0; k < KNN; ++k) wcs[tid * 21 + k] = wr[k] * scale;
        }
        __syncthreads();             // block-uniform (whole block 0 enters)
        // B[k=(lane>>4)*8+j][f=tile*16+(lane&15)] (f16), M: C/D-layout m_last
        const int lane = tid & 63, tile = tid >> 6;
        const int q = lane >> 4, c = lane & 15;
        const int f = tile * 16 + c;
        half8 hb;
        #pragma unroll
        for (int j = 0; j < 8; ++j) {
            const int k = q * 8 + j;
            float val = 0.f;
            if (k < KNN && f < 50) {
                #pragma unroll
                for (int cc = 0; cc < 30; ++cc)
                    val = fmaf(wcs[cc * 21 + k], smix2[cc * 50 + f], val);
            }
            hb[j] = (_Float16)val;
        }
        Bf[tile * 64 + lane] = hb;
        f32x4 mf;
        #pragma unroll
        for (int r = 0; r < 4; ++r)
            mf[r] = (f < 50) ? m_last[(q * 4 + r) * 50 + f] : 0.f;
        Mf[tile * 64 + lane] = mf;
    }

    const int t = tid & 63, w = tid >> 6;
    const int row = bidx * 4 + w;
    const int n = row & 511;

    // lane-parallel softmax(w_fm1): lane t<20 ends with swn[t] in mysw
    float mx = w_fm1[0];
    #pragma unroll
    for (int k = 1; k < KNN; ++k) mx = fmaxf(mx, w_fm1[k]);
    float ex = (t < KNN) ? __expf(w_fm1[t] - mx) : 0.f;
    float ssum = ex;
    #pragma unroll
    for (int off = 1; off <= 32; off <<= 1) ssum += __shfl_xor(ssum, off, 64);
    const float mysw = ex / ssum;

    const float4* xn4 = (const float4*)(xb + n * 16);
    const float4 o0 = xn4[0], o1 = xn4[1], o2 = xn4[2], o3 = xn4[3];
    const float sqn = dot16(o0, o1, o2, o3, o0, o1, o2, o3);

    unsigned cd[8];
    scan_candidates(xb, sqn, t, o0, o1, o2, o3, cd);
    const int nbrv = merge20(cd, t);

    // gather: lane covers e = j*64+t -> (k = e>>4, d = e&15)
    float nrf[5];
    #pragma unroll
    for (int j = 0; j < 5; ++j) {
        const int e = j * 64 + t;
        const int nb = __shfl(nbrv, e >> 4, 64);
        nrf[j] = xb[nb * 16 + (e & 15)];
    }
    // partial wFM: lane t sums its 5 k's for d = t&15 (k = j*4 + (t>>4))
    const int kq = t >> 4;
    float part = 0.f;
    #pragma unroll
    for (int j = 0; j < 5; ++j) {
        const float swk = __shfl(mysw, j * 4 + kq, 64);
        part = fmaf(swk, nrf[j], part);
    }
    part += __shfl_xor(part, 16, 64);
    part += __shfl_xor(part, 32, 64);
    if (t < 16) R[(size_t)row * 16 + t] = part;
}

// ---------------------------------------------------------------------------
// Stage 2: KNN on R (inline norms, diag exact 0) + MFMA-fused wFM2.mix2 +
// manifold dist + pool + classifier atomics. One barrier (epilogue only).
// ---------------------------------------------------------------------------
__global__ __launch_bounds__(256)
void stage2_kernel(const float* __restrict__ Rg,
                   const half8* __restrict__ Bfrag, const f32x4* __restrict__ Mfrag,
                   const float* __restrict__ w_cls, float* __restrict__ out) {
    __shared__ float NRs[4][344];    // [wave][20*17+pad] (stride 17 -> <=2-way)
    __shared__ float pool4[4];
    const int tid   = threadIdx.x;
    const int bidx  = blockIdx.x;
    const int batch = bidx >> 7;
    const float* Rb = Rg + (size_t)batch * 8192;

    const int t = tid & 63, w = tid >> 6;
    const int row = bidx * 4 + w;
    const int n = row & 511;

    const float4* rn4 = (const float4*)(Rb + n * 16);
    const float4 o0 = rn4[0], o1 = rn4[1], o2 = rn4[2], o3 = rn4[3];
    const float sqn = dot16(o0, o1, o2, o3, o0, o1, o2, o3);

    unsigned cd[8];
    scan_candidates(Rb, sqn, t, o0, o1, o2, o3, cd);
    const int nbrv = merge20(cd, t);

    // gather neighbor rows, bounce through padded LDS (wave-internal order)
    #pragma unroll
    for (int j = 0; j < 5; ++j) {
        const int e = j * 64 + t;
        const int nb = __shfl(nbrv, e >> 4, 64);
        NRs[w][(e >> 4) * 17 + (e & 15)] = Rb[nb * 16 + (e & 15)];
    }

    // A-fragment: A[m = t&15][k = (t>>4)*8+j] = NR[k][m], zero for k >= 20
    const int q = t >> 4, c = t & 15;
    half8 af;
    #pragma unroll
    for (int j = 0; j < 8; ++j) {
        const int k = q * 8 + j;
        af[j] = (k < KNN) ? (_Float16)NRs[w][k * 17 + c] : (_Float16)0.f;
    }

    float dsum = 0.f;
    #pragma unroll
    for (int tile = 0; tile < 4; ++tile) {
        const half8 bf = Bfrag[tile * 64 + t];
        const f32x4 mf = Mfrag[tile * 64 + t];
        f32x4 acc = {0.f, 0.f, 0.f, 0.f};
        acc = __builtin_amdgcn_mfma_f32_16x16x32_f16(af, bf, acc, 0, 0, 0);
        float a2 = 0.f;
        #pragma unroll
        for (int r = 0; r < 4; ++r) {
            const float diff = acc[r] - mf[r];
            a2 = fmaf(diff, diff, a2);
        }
        a2 += __shfl_xor(a2, 16, 64);
        a2 += __shfl_xor(a2, 32, 64);
        const int f = tile * 16 + c;
        dsum += (f < 50) ? sqrtf(a2 + 1e-8f) : 0.f;
    }
    // wave sum counts each f 4x (column replication) -> /4; pooled = /50
    #pragma unroll
    for (int off = 32; off >= 1; off >>= 1) dsum += __shfl_xor(dsum, off, 64);
    if (t == 0) pool4[w] = dsum * (1.0f / 200.0f);
    __syncthreads();

    if (tid < 40) {
        const int n0 = (bidx * 4) & 511;
        float a = 0.f;
        #pragma unroll
        for (int i = 0; i < 4; ++i)
            a = fmaf(pool4[i], w_cls[(n0 + i) * 40 + tid], a);
        unsafeAtomicAdd(&out[batch * 40 + tid], a);
    }
}

extern "C" void kernel_launch(void* const* d_in, const int* in_sizes, int n_in,
                              void* d_out, int out_size, void* d_ws, size_t ws_size,
                              hipStream_t stream) {
    const float* x      = (const float*)d_in[0];
    const float* w_fm1  = (const float*)d_in[1];
    const float* w_mix1 = (const float*)d_in[2];
    const float* w_fm2  = (const float*)d_in[3];
    const float* w_mix2 = (const float*)d_in[4];
    const float* m_last = (const float*)d_in[5];
    const float* w_cls  = (const float*)d_in[6];
    const float* b_cls  = (const float*)d_in[7];
    float* out = (float*)d_out;

    float* ws  = (float*)d_ws;
    float* R   = ws;                          // 131072 floats
    half8* Bf  = (half8*)(ws + 131072);       // 256 x 16 B
    f32x4* Mf  = (f32x4*)(ws + 132096);       // 256 x 16 B

    stage1_kernel<<<2048, 256, 0, stream>>>(x, w_fm1, w_fm2, w_mix1, w_mix2,
                                            m_last, b_cls, R, Bf, Mf, out);
    stage2_kernel<<<2048, 256, 0, stream>>>(R, Bf, Mf, w_cls, out);
}